// Round 5
// baseline (450.388 us; speedup 1.0000x reference)
//
#include <hip/hip_runtime.h>
#include <hip/hip_bf16.h>
#include <math.h>
#include <float.h>

// x: [4,128,256,256] f32; conv_w: [4,128,128]; conv_g/b: [4,128]
// final_w: [128,640]; final_g/b: [128]; out: [4,128,256,256] f32
#define B_ 4
#define C_ 128
#define P_ 65536

// ---- workspace float offsets ----
#define M3_OFF      0        // [512][64] block maxima (32x32), exact fp32
#define M2_OFF      32768    // [512][16]
#define M1_OFF      40960    // [512][4]
#define M0_OFF      43008    // [512]
#define YBASE_      43520    // y levels, same internal layout as M
#define SCALED_OFF  87040    // [4][128]
#define SHIFTD_OFF  87552    // [4][128]
#define CONTRIB_OFF 88064    // [4][128][64]
#define S3_OFF      120832   // [512][64] block sums (32x32), exact fp32
#define SX_OFF      153600   // [512] per-(b,c) total sum
#define G_OFF       154112   // [4][128][128] Gram (bf16-sourced, fp32 accum)
#define SCALEF_OFF  219648   // [128]
#define SHIFTF_OFF  219776   // [128]
#define MAXP_OFF    219904   // [512 wg][128 c][8 j3] fp32 max partials
#define SUMP_OFF    744192   // [512 wg][128 c][8 j3] fp32 sum partials
// total floats: 1268480 (~4.84 MB)

using short8 = __attribute__((ext_vector_type(8))) short;
using f32x4 = __attribute__((ext_vector_type(4))) float;

__device__ __forceinline__ int level_rel(int d) {
    return YBASE_ - 512 * (((1 << (2 * (d + 1))) - 1) / 3);
}

// RNE pack of two f32 into bf16x2 (low = first arg)
__device__ __forceinline__ unsigned int bfpair(float a, float b) {
    unsigned int ua = __float_as_uint(a), ub = __float_as_uint(b);
    ua = (ua + 0x7fffu + ((ua >> 16) & 1u)) >> 16;
    ub = (ub + 0x7fffu + ((ub >> 16) & 1u)) & 0xffff0000u;
    return ua | ub;
}

// K1: fused pass over x: exact fp32 32-col-block max/sum partials (from the
// fp32 registers, BEFORE bf16 rounding) + bf16 Gram partials via MFMA.
// grid = 512 (b*128 + rowchunk rc covering image rows 2rc..2rc+1), block 256.
__global__ __launch_bounds__(256) void k_gram_pool(const float* __restrict__ x,
                                                   float* __restrict__ ws,
                                                   float* __restrict__ gpart) {
    __shared__ uint4 tileq[2048];  // [128 c][128 p] bf16, XOR-swizzled, 32KB
    unsigned char* tile = (unsigned char*)tileq;
    int wg = blockIdx.x;
    int b = wg >> 7, rc = wg & 127;
    const float* xb = x + (size_t)b * C_ * P_ + (size_t)rc * 512;
    int t = threadIdx.x, l = t & 63, wv = t >> 6;
    int pq = t & 31, ci = t >> 5;

    f32x4 acc[2][8];
#pragma unroll
    for (int i = 0; i < 2; ++i)
#pragma unroll
        for (int j = 0; j < 8; ++j) acc[i][j] = (f32x4){0.f, 0.f, 0.f, 0.f};
    // per-thread max/sum accumulators: [k][row-parity], all statically indexed
    float mx[16][2], sm[16][2];
#pragma unroll
    for (int k = 0; k < 16; ++k)
#pragma unroll
        for (int par = 0; par < 2; ++par) { mx[k][par] = -FLT_MAX; sm[k][par] = 0.f; }

#pragma unroll
    for (int s = 0; s < 4; ++s) {
        // stage: fp32 -> bf16 tile; fold fp32 max/sum on the way
#pragma unroll
        for (int k = 0; k < 16; ++k) {
            int c = ci + 8 * k;
            float4 v = *(const float4*)(xb + (size_t)c * P_ + s * 128 + pq * 4);
            mx[k][s & 1] = fmaxf(mx[k][s & 1],
                                 fmaxf(fmaxf(v.x, v.y), fmaxf(v.z, v.w)));
            sm[k][s & 1] += (v.x + v.y) + (v.z + v.w);
            unsigned int u0 = bfpair(v.x, v.y), u1 = bfpair(v.z, v.w);
            int wa = (c * 256 + pq * 8) ^ ((c & 7) << 4);
            *(uint2*)(tile + wa) = make_uint2(u0, u1);
        }
        __syncthreads();
        // Gram MFMA: wave wv owns m-tiles {2wv, 2wv+1} x all 8 n-tiles
#pragma unroll
        for (int ks = 0; ks < 4; ++ks) {
            int col = ks * 64 + (l >> 4) * 16;
            int ra0 = (((2 * wv) * 16 + (l & 15)) * 256 + col) ^ ((l & 7) << 4);
            int ra1 = (((2 * wv + 1) * 16 + (l & 15)) * 256 + col) ^ ((l & 7) << 4);
            short8 a0 = *(const short8*)(tile + ra0);
            short8 a1 = *(const short8*)(tile + ra1);
#pragma unroll
            for (int nt = 0; nt < 8; ++nt) {
                int rb = ((nt * 16 + (l & 15)) * 256 + col) ^ ((l & 7) << 4);
                short8 bb = *(const short8*)(tile + rb);
                acc[0][nt] = __builtin_amdgcn_mfma_f32_16x16x32_bf16(a0, bb, acc[0][nt], 0, 0, 0);
                acc[1][nt] = __builtin_amdgcn_mfma_f32_16x16x32_bf16(a1, bb, acc[1][nt], 0, 0, 0);
            }
        }
        __syncthreads();
    }
    // write Gram partials to gpart[wg][128][128] (G symmetric -> C/D row/col
    // convention self-consistent)
    size_t gb = (size_t)wg * 16384;
#pragma unroll
    for (int mt2 = 0; mt2 < 2; ++mt2) {
        int mt = wv * 2 + mt2;
#pragma unroll
        for (int nt = 0; nt < 8; ++nt)
#pragma unroll
            for (int r = 0; r < 4; ++r)
                gpart[gb + (size_t)(mt * 16 + (l >> 4) * 4 + r) * 128 + nt * 16 + (l & 15)] =
                    acc[mt2][nt][r];
    }
    // reduce max/sum over the 8 lanes sharing a 32-col block (pq bits 0..2),
    // then writer lanes (pq&7==0) emit the (c, j3) partial for this row-pair.
#pragma unroll
    for (int k = 0; k < 16; ++k)
#pragma unroll
        for (int par = 0; par < 2; ++par) {
            float m = mx[k][par], s2 = sm[k][par];
            m = fmaxf(m, __shfl_xor(m, 1)); s2 += __shfl_xor(s2, 1);
            m = fmaxf(m, __shfl_xor(m, 2)); s2 += __shfl_xor(s2, 2);
            m = fmaxf(m, __shfl_xor(m, 4)); s2 += __shfl_xor(s2, 4);
            if ((pq & 7) == 0) {
                int c = ci + 8 * k;
                int j3 = par * 4 + (pq >> 3);
                ws[MAXP_OFF + (size_t)wg * 1024 + c * 8 + j3] = m;
                ws[SUMP_OFF + (size_t)wg * 1024 + c * 8 + j3] = s2;
            }
        }
}

// K2a: reduce Gram partials over 128 row-chunks per b. grid = 256, block 256
__global__ __launch_bounds__(256) void k_reduceG(const float* __restrict__ gpart,
                                                 float* __restrict__ ws) {
    int tid = blockIdx.x * 256 + threadIdx.x;  // 65536
    int b = tid >> 14, inner = tid & 16383;
    const float* p = gpart + (size_t)b * 128 * 16384 + inner;
    float s = 0.f;
    for (int r = 0; r < 128; ++r) s += p[(size_t)r * 16384];
    ws[G_OFF + tid] = s;
}

// K2b: reduce max/sum partials -> M3/S3/SX + pyramid levels. grid = 2, block 256
__global__ __launch_bounds__(256) void k_reduceMS(float* __restrict__ ws) {
    int bc = blockIdx.x * 256 + threadIdx.x;
    if (bc >= 512) return;
    int b = bc >> 7, c = bc & 127;
    float sx = 0.f;
    for (int blk = 0; blk < 64; ++blk) {
        int i = blk >> 3, j = blk & 7;
        float mx = -FLT_MAX, sm = 0.f;
        for (int rr = 0; rr < 16; ++rr) {
            size_t idx = (size_t)(b * 128 + i * 16 + rr) * 1024 + c * 8 + j;
            mx = fmaxf(mx, ws[MAXP_OFF + idx]);
            sm += ws[SUMP_OFF + idx];
        }
        ws[M3_OFF + (size_t)bc * 64 + blk] = mx;
        ws[S3_OFF + (size_t)bc * 64 + blk] = sm;
        sx += sm;
    }
    ws[SX_OFF + bc] = sx;
    // pyramid
    const float* M3 = ws + (size_t)bc * 64;
    float* M2 = ws + M2_OFF + (size_t)bc * 16;
    float* M1 = ws + M1_OFF + (size_t)bc * 4;
    float m2[16];
#pragma unroll
    for (int i2 = 0; i2 < 4; ++i2)
#pragma unroll
        for (int j2 = 0; j2 < 4; ++j2) {
            float m = -FLT_MAX;
            for (int a = 0; a < 2; ++a)
                for (int b2 = 0; b2 < 2; ++b2)
                    m = fmaxf(m, M3[(2 * i2 + a) * 8 + (2 * j2 + b2)]);
            m2[i2 * 4 + j2] = m;
            M2[i2 * 4 + j2] = m;
        }
    float m1[4];
#pragma unroll
    for (int i1 = 0; i1 < 2; ++i1)
#pragma unroll
        for (int j1 = 0; j1 < 2; ++j1) {
            float m = -FLT_MAX;
            for (int a = 0; a < 2; ++a)
                for (int b2 = 0; b2 < 2; ++b2)
                    m = fmaxf(m, m2[(2 * i1 + a) * 4 + (2 * j1 + b2)]);
            m1[i1 * 2 + j1] = m;
            M1[i1 * 2 + j1] = m;
        }
    ws[M0_OFF + bc] = fmaxf(fmaxf(m1[0], m1[1]), fmaxf(m1[2], m1[3]));
}

// K3a: y_d[b,co,blk] = sum_ci M_d[b,ci,blk] * conv_w[d][co][ci]
__global__ __launch_bounds__(256) void k_conv_pool(const float* __restrict__ conv_w,
                                                   float* __restrict__ ws) {
    int bid = blockIdx.x;
    int d = bid >> 4, b = (bid >> 2) & 3, cchunk = bid & 3;
    int NB = 1 << (2 * d);
    int rel = level_rel(d);
    const float* Mb = ws + rel + (size_t)b * 128 * NB;
    float* Yb = ws + YBASE_ + rel + (size_t)b * 128 * NB;
    __shared__ float mlds[8192];
    int t = threadIdx.x;
    int tot = 128 * NB;
    for (int i = t; i < tot; i += 256) mlds[i] = Mb[i];
    __syncthreads();
    if (NB >= 4) {
        int nbq = NB >> 2;
        int nq = 32 * nbq;
        for (int qi = t; qi < nq; qi += 256) {
            int co = cchunk * 32 + (qi >> (2 * d - 2));
            int bq = qi & (nbq - 1);
            const float* wrow = conv_w + ((size_t)d * 128 + co) * 128;
            float a0 = 0.f, a1 = 0.f, a2 = 0.f, a3 = 0.f;
            for (int ci = 0; ci < 128; ++ci) {
                float4 mv = *(const float4*)(&mlds[ci * NB + bq * 4]);
                float wvv = wrow[ci];
                a0 = fmaf(wvv, mv.x, a0);
                a1 = fmaf(wvv, mv.y, a1);
                a2 = fmaf(wvv, mv.z, a2);
                a3 = fmaf(wvv, mv.w, a3);
            }
            float4 r;
            r.x = a0; r.y = a1; r.z = a2; r.w = a3;
            *(float4*)(&Yb[co * NB + bq * 4]) = r;
        }
    } else {
        for (int oi = t; oi < 32; oi += 256) {
            int co = cchunk * 32 + oi;
            const float* wrow = conv_w + (size_t)co * 128;
            float acc = 0.f;
            for (int ci = 0; ci < 128; ++ci) acc = fmaf(mlds[ci], wrow[ci], acc);
            Yb[co] = acc;
        }
    }
}

// K3b: per-(d,c) BN stats
__global__ __launch_bounds__(256) void k_bnstats_d(const float* __restrict__ conv_g,
                                                   const float* __restrict__ conv_b,
                                                   float* __restrict__ ws) {
    int tid = blockIdx.x * 256 + threadIdx.x;
    if (tid >= 512) return;
    int d = tid >> 7, c = tid & 127;
    int NB = 1 << (2 * d);
    const float* Y = ws + YBASE_ + level_rel(d);
    int n = 4 * NB;
    float s = 0.f;
    for (int b = 0; b < 4; ++b)
        for (int k = 0; k < NB; ++k) s += Y[((size_t)b * 128 + c) * NB + k];
    float mean = s / (float)n;
    float v = 0.f;
    for (int b = 0; b < 4; ++b)
        for (int k = 0; k < NB; ++k) {
            float dd = Y[((size_t)b * 128 + c) * NB + k] - mean;
            v = fmaf(dd, dd, v);
        }
    float var = v / (float)n;
    float sc = conv_g[d * 128 + c] * rsqrtf(var + 1e-5f);
    ws[SCALED_OFF + tid] = sc;
    ws[SHIFTD_OFF + tid] = conv_b[d * 128 + c] - mean * sc;
}

// K3c: contrib[b][o][blk3]. grid = B*64, block 128 (thread = o)
__global__ __launch_bounds__(128) void k_contrib(const float* __restrict__ final_w,
                                                 float* __restrict__ ws) {
    int b = blockIdx.x >> 6, blk3 = blockIdx.x & 63;
    int i3 = blk3 >> 3, j3 = blk3 & 7;
    __shared__ float pn[512];
    int t = threadIdx.x;
    for (int k = t; k < 512; k += 128) {
        int d = k >> 7, c = k & 127;
        int sh = 3 - d;
        int blkd = (i3 >> sh) * (1 << d) + (j3 >> sh);
        int NB = 1 << (2 * d);
        float yv = ws[YBASE_ + level_rel(d) + ((size_t)b * 128 + c) * NB + blkd];
        pn[k] = yv * ws[SCALED_OFF + k] + ws[SHIFTD_OFF + k];
    }
    __syncthreads();
    const float* fw = final_w + (size_t)t * 640 + 128;
    float acc = 0.f;
#pragma unroll 8
    for (int k = 0; k < 512; k += 4) {
        float4 f = *(const float4*)(fw + k);
        acc = fmaf(pn[k], f.x, acc);
        acc = fmaf(pn[k + 1], f.y, acc);
        acc = fmaf(pn[k + 2], f.z, acc);
        acc = fmaf(pn[k + 3], f.w, acc);
    }
    ws[CONTRIB_OFF + ((size_t)b * 128 + t) * 64 + blk3] = acc;
}

// K4: closed-form final BN stats: sum(z^2) = wGw + 2*sum_blk cv*(w.S3) + 1024*sum cv^2
// grid = 128 (o), block 128 (t = c)
__global__ __launch_bounds__(128) void k_stats(const float* __restrict__ final_w,
                                               const float* __restrict__ final_g,
                                               const float* __restrict__ final_b,
                                               float* __restrict__ ws) {
    int o = blockIdx.x, t = threadIdx.x;
    __shared__ __align__(16) float wlds[128];
    __shared__ __align__(16) float cvl[64];
    __shared__ float rbuf[4];
    wlds[t] = final_w[(size_t)o * 640 + t];
    __syncthreads();
    float SSQ = 0.f, SUM = 0.f;
    for (int b = 0; b < 4; ++b) {
        if (t < 64) cvl[t] = ws[CONTRIB_OFF + (size_t)(b * 128 + o) * 64 + t];
        __syncthreads();
        const float* Gb = ws + G_OFF + (size_t)b * 16384 + (size_t)t * 128;
        float a1 = 0.f;
#pragma unroll 8
        for (int k = 0; k < 128; k += 4) {
            float4 g = *(const float4*)(Gb + k);
            float4 w = *(const float4*)(&wlds[k]);
            a1 = fmaf(g.x, w.x, fmaf(g.y, w.y, fmaf(g.z, w.z, fmaf(g.w, w.w, a1))));
        }
        const float* S3p = ws + S3_OFF + (size_t)(b * 128 + t) * 64;
        float a2 = 0.f;
#pragma unroll 8
        for (int k = 0; k < 64; k += 4) {
            float4 sv = *(const float4*)(S3p + k);
            float4 cv = *(const float4*)(&cvl[k]);
            a2 = fmaf(sv.x, cv.x, fmaf(sv.y, cv.y, fmaf(sv.z, cv.z, fmaf(sv.w, cv.w, a2))));
        }
        float r1 = (a1 + 2.f * a2) * wlds[t];
        float r2 = wlds[t] * ws[SX_OFF + b * 128 + t];
        if (t < 64) {
            r1 += 1024.f * cvl[t] * cvl[t];
            r2 += 1024.f * cvl[t];
        }
#pragma unroll
        for (int k = 1; k < 64; k <<= 1) {
            r1 += __shfl_xor(r1, k);
            r2 += __shfl_xor(r2, k);
        }
        if ((t & 63) == 0) {
            rbuf[(t >> 6) * 2] = r1;
            rbuf[(t >> 6) * 2 + 1] = r2;
        }
        __syncthreads();
        SSQ += rbuf[0] + rbuf[2];
        SUM += rbuf[1] + rbuf[3];
        __syncthreads();
    }
    if (t == 0) {
        float mean = SUM / 262144.f;
        float var = SSQ / 262144.f - mean * mean;
        float sc = final_g[o] * rsqrtf(var + 1e-5f);
        ws[SCALEF_OFF + o] = sc;
        ws[SHIFTF_OFF + o] = final_b[o] - mean * sc;
    }
}

// K5: out[b,o,p] = (MFMA(W0,x) + contrib) * scale[o] + shift[o].
// grid = 2048 (b*512 + ptile of 128), block 256 (4 waves; wave = 32 p)
__global__ __launch_bounds__(256) void k_out(const float* __restrict__ x,
                                             const float* __restrict__ final_w,
                                             const float* __restrict__ ws,
                                             float* __restrict__ out) {
    __shared__ uint4 wtileq[2048];  // [128 o][128 c] bf16, swizzled, 32KB
    __shared__ float scl[128], shf[128], cvs[512];
    unsigned char* wtile = (unsigned char*)wtileq;
    int wgid = blockIdx.x;
    int b = wgid >> 9, pt = wgid & 511;
    int p0 = pt * 128;
    int t = threadIdx.x, l = t & 63, wv = t >> 6;
    // stage W0 (cols 0..127 of final_w) as bf16 [o][c]
#pragma unroll
    for (int it = 0; it < 32; ++it) {
        int pid = it * 256 + t;  // 8192 pairs
        int o = pid >> 6, cp = (pid & 63) * 2;
        float2 f = *(const float2*)(final_w + (size_t)o * 640 + cp);
        unsigned int u = bfpair(f.x, f.y);
        int wa = (o * 256 + cp * 2) ^ ((o & 7) << 4);
        *(unsigned int*)(wtile + wa) = u;
    }
    if (t < 128) {
        scl[t] = ws[SCALEF_OFF + t];
        shf[t] = ws[SHIFTF_OFF + t];
    }
    int i3 = pt >> 6, jb = (pt & 1) * 4;
    for (int q = t; q < 512; q += 256) {
        int o = q >> 2, jj = q & 3;
        cvs[q] = ws[CONTRIB_OFF + (size_t)(b * 128 + o) * 64 + i3 * 8 + jb + jj];
    }
    __syncthreads();

    const float* xb = x + (size_t)b * C_ * P_;
    int pw = p0 + wv * 32;
    f32x4 acc[8][2];
#pragma unroll
    for (int i = 0; i < 8; ++i) {
        acc[i][0] = (f32x4){0.f, 0.f, 0.f, 0.f};
        acc[i][1] = (f32x4){0.f, 0.f, 0.f, 0.f};
    }
#pragma unroll
    for (int ks = 0; ks < 4; ++ks) {
        short8 bf[2];
#pragma unroll
        for (int nt = 0; nt < 2; ++nt) {
            const float* xp = xb + (size_t)(ks * 32 + (l >> 4) * 8) * P_ + (pw + nt * 16 + (l & 15));
            float f0 = xp[0 * P_], f1 = xp[1 * P_], f2 = xp[2 * P_], f3 = xp[3 * P_];
            float f4 = xp[4 * P_], f5 = xp[5 * P_], f6 = xp[6 * P_], f7 = xp[7 * P_];
            union { uint4 u; short8 s; } cvtu;
            cvtu.u = make_uint4(bfpair(f0, f1), bfpair(f2, f3), bfpair(f4, f5), bfpair(f6, f7));
            bf[nt] = cvtu.s;
        }
#pragma unroll
        for (int mt = 0; mt < 8; ++mt) {
            int ra = ((mt * 16 + (l & 15)) * 256 + ks * 64 + (l >> 4) * 16) ^ ((l & 7) << 4);
            short8 af = *(const short8*)(wtile + ra);
            acc[mt][0] = __builtin_amdgcn_mfma_f32_16x16x32_bf16(af, bf[0], acc[mt][0], 0, 0, 0);
            acc[mt][1] = __builtin_amdgcn_mfma_f32_16x16x32_bf16(af, bf[1], acc[mt][1], 0, 0, 0);
        }
    }
    // epilogue: +contrib, *scale+shift, store
#pragma unroll
    for (int mt = 0; mt < 8; ++mt)
#pragma unroll
        for (int nt = 0; nt < 2; ++nt) {
            int p = pw + nt * 16 + (l & 15);
            int jj = ((p & 255) >> 5) & 3;
#pragma unroll
            for (int r = 0; r < 4; ++r) {
                int o = mt * 16 + (l >> 4) * 4 + r;
                float z = acc[mt][nt][r] + cvs[o * 4 + jj];
                out[(size_t)(b * 128 + o) * P_ + p] = fmaf(z, scl[o], shf[o]);
            }
        }
}

extern "C" void kernel_launch(void* const* d_in, const int* in_sizes, int n_in,
                              void* d_out, int out_size, void* d_ws, size_t ws_size,
                              hipStream_t stream) {
    const float* x = (const float*)d_in[0];
    const float* conv_w = (const float*)d_in[1];
    const float* conv_g = (const float*)d_in[2];
    const float* conv_b = (const float*)d_in[3];
    const float* final_w = (const float*)d_in[4];
    const float* final_g = (const float*)d_in[5];
    const float* final_b = (const float*)d_in[6];
    float* out = (float*)d_out;
    float* ws = (float*)d_ws;

    // single fused pass over x: fp32-exact block max/sum partials + bf16 Gram
    // (Gram partials live in d_out scratch until k_reduceG; k_out overwrites d_out)
    k_gram_pool<<<512, 256, 0, stream>>>(x, ws, out);
    k_reduceG<<<256, 256, 0, stream>>>(out, ws);
    k_reduceMS<<<2, 256, 0, stream>>>(ws);
    k_conv_pool<<<64, 256, 0, stream>>>(conv_w, ws);
    k_bnstats_d<<<2, 256, 0, stream>>>(conv_g, conv_b, ws);
    k_contrib<<<B_ * 64, 128, 0, stream>>>(final_w, ws);
    k_stats<<<128, 128, 0, stream>>>(final_w, final_g, final_b, ws);
    k_out<<<2048, 256, 0, stream>>>(x, final_w, ws, out);
}

// Round 6
// 209.339 us; speedup vs baseline: 2.1515x; 2.1515x over previous
//
#include <hip/hip_runtime.h>
#include <hip/hip_bf16.h>
#include <math.h>
#include <float.h>

// x: [4,128,256,256] f32; conv_w: [4,128,128]; conv_g/b: [4,128]
// final_w: [128,640]; final_g/b: [128]; out: [4,128,256,256] f32
#define B_ 4
#define C_ 128
#define P_ 65536

// ---- workspace float offsets ----
#define M3_OFF      0        // [512][64] block maxima (32x32), exact fp32
#define M2_OFF      32768    // [512][16]
#define M1_OFF      40960    // [512][4]
#define M0_OFF      43008    // [512]
#define YBASE_      43520    // y levels, same internal layout as M
#define SCALED_OFF  87040    // [4][128]
#define SHIFTD_OFF  87552    // [4][128]
#define CONTRIB_OFF 88064    // [4][128][64]
#define S3_OFF      120832   // [512][64] block sums (32x32), exact fp32
#define SX_OFF      153600   // [512] per-(b,c) total sum
#define G_OFF       154112   // [4][128][128] Gram (bf16-sourced, fp32 accum)
#define SCALEF_OFF  219648   // [128]
#define SHIFTF_OFF  219776   // [128]
#define MAXP_OFF    219904   // [512 bc][64 blk][16 rr] fp32 max partials (coalesced-reduce layout)
#define SUMP_OFF    744192   // [512 bc][64 blk][16 rr] fp32 sum partials
// total floats: 1268480 (~4.84 MB)

using short8 = __attribute__((ext_vector_type(8))) short;
using f32x4 = __attribute__((ext_vector_type(4))) float;

__device__ __forceinline__ int level_rel(int d) {
    return YBASE_ - 512 * (((1 << (2 * (d + 1))) - 1) / 3);
}

// RNE pack of two f32 into bf16x2 (low = first arg)
__device__ __forceinline__ unsigned int bfpair(float a, float b) {
    unsigned int ua = __float_as_uint(a), ub = __float_as_uint(b);
    ua = (ua + 0x7fffu + ((ua >> 16) & 1u)) >> 16;
    ub = (ub + 0x7fffu + ((ub >> 16) & 1u)) & 0xffff0000u;
    return ua | ub;
}

// K1: fused pass over x: exact fp32 32-col-block max/sum partials (from the
// fp32 registers, BEFORE bf16 rounding) + bf16 Gram partials via MFMA.
// grid = 512 (b*128 + rowchunk rc covering image rows 2rc..2rc+1), block 256.
__global__ __launch_bounds__(256) void k_gram_pool(const float* __restrict__ x,
                                                   float* __restrict__ ws,
                                                   float* __restrict__ gpart) {
    __shared__ uint4 tileq[2048];  // [128 c][128 p] bf16, XOR-swizzled, 32KB
    unsigned char* tile = (unsigned char*)tileq;
    int wg = blockIdx.x;
    int b = wg >> 7, rc = wg & 127;
    const float* xb = x + (size_t)b * C_ * P_ + (size_t)rc * 512;
    int t = threadIdx.x, l = t & 63, wv = t >> 6;
    int pq = t & 31, ci = t >> 5;

    f32x4 acc[2][8];
#pragma unroll
    for (int i = 0; i < 2; ++i)
#pragma unroll
        for (int j = 0; j < 8; ++j) acc[i][j] = (f32x4){0.f, 0.f, 0.f, 0.f};
    // per-thread max/sum accumulators: [k][row-parity], all statically indexed
    float mx[16][2], sm[16][2];
#pragma unroll
    for (int k = 0; k < 16; ++k)
#pragma unroll
        for (int par = 0; par < 2; ++par) { mx[k][par] = -FLT_MAX; sm[k][par] = 0.f; }

#pragma unroll
    for (int s = 0; s < 4; ++s) {
        // stage: fp32 -> bf16 tile; fold fp32 max/sum on the way
#pragma unroll
        for (int k = 0; k < 16; ++k) {
            int c = ci + 8 * k;
            float4 v = *(const float4*)(xb + (size_t)c * P_ + s * 128 + pq * 4);
            mx[k][s & 1] = fmaxf(mx[k][s & 1],
                                 fmaxf(fmaxf(v.x, v.y), fmaxf(v.z, v.w)));
            sm[k][s & 1] += (v.x + v.y) + (v.z + v.w);
            unsigned int u0 = bfpair(v.x, v.y), u1 = bfpair(v.z, v.w);
            int wa = (c * 256 + pq * 8) ^ ((c & 7) << 4);
            *(uint2*)(tile + wa) = make_uint2(u0, u1);
        }
        __syncthreads();
        // Gram MFMA: wave wv owns m-tiles {2wv, 2wv+1} x all 8 n-tiles
#pragma unroll
        for (int ks = 0; ks < 4; ++ks) {
            int col = ks * 64 + (l >> 4) * 16;
            int ra0 = (((2 * wv) * 16 + (l & 15)) * 256 + col) ^ ((l & 7) << 4);
            int ra1 = (((2 * wv + 1) * 16 + (l & 15)) * 256 + col) ^ ((l & 7) << 4);
            short8 a0 = *(const short8*)(tile + ra0);
            short8 a1 = *(const short8*)(tile + ra1);
#pragma unroll
            for (int nt = 0; nt < 8; ++nt) {
                int rb = ((nt * 16 + (l & 15)) * 256 + col) ^ ((l & 7) << 4);
                short8 bb = *(const short8*)(tile + rb);
                acc[0][nt] = __builtin_amdgcn_mfma_f32_16x16x32_bf16(a0, bb, acc[0][nt], 0, 0, 0);
                acc[1][nt] = __builtin_amdgcn_mfma_f32_16x16x32_bf16(a1, bb, acc[1][nt], 0, 0, 0);
            }
        }
        __syncthreads();
    }
    // write Gram partials to gpart[wg][128][128] (G symmetric -> C/D row/col
    // convention self-consistent)
    size_t gb = (size_t)wg * 16384;
#pragma unroll
    for (int mt2 = 0; mt2 < 2; ++mt2) {
        int mt = wv * 2 + mt2;
#pragma unroll
        for (int nt = 0; nt < 8; ++nt)
#pragma unroll
            for (int r = 0; r < 4; ++r)
                gpart[gb + (size_t)(mt * 16 + (l >> 4) * 4 + r) * 128 + nt * 16 + (l & 15)] =
                    acc[mt2][nt][r];
    }
    // reduce max/sum over the 8 lanes sharing a 32-col block (pq bits 0..2),
    // writers emit partial at [bc][blk][rr] so the next reduce is unit-stride.
    int i3 = rc >> 4, rr = rc & 15;
#pragma unroll
    for (int k = 0; k < 16; ++k)
#pragma unroll
        for (int par = 0; par < 2; ++par) {
            float m = mx[k][par], s2 = sm[k][par];
            m = fmaxf(m, __shfl_xor(m, 1)); s2 += __shfl_xor(s2, 1);
            m = fmaxf(m, __shfl_xor(m, 2)); s2 += __shfl_xor(s2, 2);
            m = fmaxf(m, __shfl_xor(m, 4)); s2 += __shfl_xor(s2, 4);
            if ((pq & 7) == 0) {
                int c = ci + 8 * k;
                int j3 = par * 4 + (pq >> 3);
                size_t idx = ((size_t)(b * 128 + c) * 64 + i3 * 8 + j3) * 16 + rr;
                ws[MAXP_OFF + idx] = m;
                ws[SUMP_OFF + idx] = s2;
            }
        }
}

// K2a: reduce Gram partials over 128 row-chunks per b. grid = 256, block 256
__global__ __launch_bounds__(256) void k_reduceG(const float* __restrict__ gpart,
                                                 float* __restrict__ ws) {
    int tid = blockIdx.x * 256 + threadIdx.x;  // 65536
    int b = tid >> 14, inner = tid & 16383;
    const float* p = gpart + (size_t)b * 128 * 16384 + inner;
    float s = 0.f;
    for (int r = 0; r < 128; ++r) s += p[(size_t)r * 16384];
    ws[G_OFF + tid] = s;
}

// K2b: reduce max/sum partials -> M3/S3/SX + pyramid. grid = 512 (bc), block 256.
// Thread quad (blk, q): float4-load 4 of the 16 contiguous rr partials.
__global__ __launch_bounds__(256) void k_reduceMS(float* __restrict__ ws) {
    int bc = blockIdx.x;  // 512
    int t = threadIdx.x;
    int blk = t >> 2, q = t & 3;
    __shared__ float bm[64], bs[64];
    __shared__ float lv[24];
    __shared__ float sxr[8];
    {
        size_t base = (size_t)bc * 1024 + blk * 16 + q * 4;
        float4 mv = *(const float4*)(ws + MAXP_OFF + base);
        float4 sv = *(const float4*)(ws + SUMP_OFF + base);
        float m = fmaxf(fmaxf(mv.x, mv.y), fmaxf(mv.z, mv.w));
        float s = (sv.x + sv.y) + (sv.z + sv.w);
        m = fmaxf(m, __shfl_xor(m, 1)); s += __shfl_xor(s, 1);
        m = fmaxf(m, __shfl_xor(m, 2)); s += __shfl_xor(s, 2);
        if (q == 0) {
            bm[blk] = m;
            bs[blk] = s;
            ws[M3_OFF + (size_t)bc * 64 + blk] = m;
            ws[S3_OFF + (size_t)bc * 64 + blk] = s;
        }
    }
    __syncthreads();
    // SX partials
    if (t < 8) {
        float sx = 0.f;
        for (int r = 0; r < 8; ++r) sx += bs[t * 8 + r];
        sxr[t] = sx;
    }
    // M2
    if (t < 16) {
        int i2 = t >> 2, j2 = t & 3;
        float m = -FLT_MAX;
        for (int a = 0; a < 2; ++a)
            for (int b2 = 0; b2 < 2; ++b2)
                m = fmaxf(m, bm[(2 * i2 + a) * 8 + 2 * j2 + b2]);
        lv[t] = m;
        ws[M2_OFF + (size_t)bc * 16 + t] = m;
    }
    __syncthreads();
    if (t == 0) {
        float sx = 0.f;
        for (int r = 0; r < 8; ++r) sx += sxr[r];
        ws[SX_OFF + bc] = sx;
    }
    // M1
    if (t < 4) {
        int i1 = t >> 1, j1 = t & 1;
        float m = -FLT_MAX;
        for (int a = 0; a < 2; ++a)
            for (int b2 = 0; b2 < 2; ++b2)
                m = fmaxf(m, lv[(2 * i1 + a) * 4 + 2 * j1 + b2]);
        lv[16 + t] = m;
        ws[M1_OFF + (size_t)bc * 4 + t] = m;
    }
    __syncthreads();
    // M0
    if (t == 0)
        ws[M0_OFF + bc] = fmaxf(fmaxf(lv[16], lv[17]), fmaxf(lv[18], lv[19]));
}

// K3a: y_d[b,co,blk] = sum_ci M_d[b,ci,blk] * conv_w[d][co][ci]
__global__ __launch_bounds__(256) void k_conv_pool(const float* __restrict__ conv_w,
                                                   float* __restrict__ ws) {
    int bid = blockIdx.x;
    int d = bid >> 4, b = (bid >> 2) & 3, cchunk = bid & 3;
    int NB = 1 << (2 * d);
    int rel = level_rel(d);
    const float* Mb = ws + rel + (size_t)b * 128 * NB;
    float* Yb = ws + YBASE_ + rel + (size_t)b * 128 * NB;
    __shared__ float mlds[8192];
    int t = threadIdx.x;
    int tot = 128 * NB;
    for (int i = t; i < tot; i += 256) mlds[i] = Mb[i];
    __syncthreads();
    if (NB >= 4) {
        int nbq = NB >> 2;
        int nq = 32 * nbq;
        for (int qi = t; qi < nq; qi += 256) {
            int co = cchunk * 32 + (qi >> (2 * d - 2));
            int bq = qi & (nbq - 1);
            const float* wrow = conv_w + ((size_t)d * 128 + co) * 128;
            float a0 = 0.f, a1 = 0.f, a2 = 0.f, a3 = 0.f;
            for (int ci = 0; ci < 128; ++ci) {
                float4 mv = *(const float4*)(&mlds[ci * NB + bq * 4]);
                float wvv = wrow[ci];
                a0 = fmaf(wvv, mv.x, a0);
                a1 = fmaf(wvv, mv.y, a1);
                a2 = fmaf(wvv, mv.z, a2);
                a3 = fmaf(wvv, mv.w, a3);
            }
            float4 r;
            r.x = a0; r.y = a1; r.z = a2; r.w = a3;
            *(float4*)(&Yb[co * NB + bq * 4]) = r;
        }
    } else {
        for (int oi = t; oi < 32; oi += 256) {
            int co = cchunk * 32 + oi;
            const float* wrow = conv_w + (size_t)co * 128;
            float acc = 0.f;
            for (int ci = 0; ci < 128; ++ci) acc = fmaf(mlds[ci], wrow[ci], acc);
            Yb[co] = acc;
        }
    }
}

// K3b: per-(d,c) BN stats
__global__ __launch_bounds__(256) void k_bnstats_d(const float* __restrict__ conv_g,
                                                   const float* __restrict__ conv_b,
                                                   float* __restrict__ ws) {
    int tid = blockIdx.x * 256 + threadIdx.x;
    if (tid >= 512) return;
    int d = tid >> 7, c = tid & 127;
    int NB = 1 << (2 * d);
    const float* Y = ws + YBASE_ + level_rel(d);
    int n = 4 * NB;
    float s = 0.f;
    for (int b = 0; b < 4; ++b)
        for (int k = 0; k < NB; ++k) s += Y[((size_t)b * 128 + c) * NB + k];
    float mean = s / (float)n;
    float v = 0.f;
    for (int b = 0; b < 4; ++b)
        for (int k = 0; k < NB; ++k) {
            float dd = Y[((size_t)b * 128 + c) * NB + k] - mean;
            v = fmaf(dd, dd, v);
        }
    float var = v / (float)n;
    float sc = conv_g[d * 128 + c] * rsqrtf(var + 1e-5f);
    ws[SCALED_OFF + tid] = sc;
    ws[SHIFTD_OFF + tid] = conv_b[d * 128 + c] - mean * sc;
}

// K3c: contrib[b][o][blk3]. grid = B*64, block 128 (thread = o)
__global__ __launch_bounds__(128) void k_contrib(const float* __restrict__ final_w,
                                                 float* __restrict__ ws) {
    int b = blockIdx.x >> 6, blk3 = blockIdx.x & 63;
    int i3 = blk3 >> 3, j3 = blk3 & 7;
    __shared__ float pn[512];
    int t = threadIdx.x;
    for (int k = t; k < 512; k += 128) {
        int d = k >> 7, c = k & 127;
        int sh = 3 - d;
        int blkd = (i3 >> sh) * (1 << d) + (j3 >> sh);
        int NB = 1 << (2 * d);
        float yv = ws[YBASE_ + level_rel(d) + ((size_t)b * 128 + c) * NB + blkd];
        pn[k] = yv * ws[SCALED_OFF + k] + ws[SHIFTD_OFF + k];
    }
    __syncthreads();
    const float* fw = final_w + (size_t)t * 640 + 128;
    float acc = 0.f;
#pragma unroll 8
    for (int k = 0; k < 512; k += 4) {
        float4 f = *(const float4*)(fw + k);
        acc = fmaf(pn[k], f.x, acc);
        acc = fmaf(pn[k + 1], f.y, acc);
        acc = fmaf(pn[k + 2], f.z, acc);
        acc = fmaf(pn[k + 3], f.w, acc);
    }
    ws[CONTRIB_OFF + ((size_t)b * 128 + t) * 64 + blk3] = acc;
}

// K4: closed-form final BN stats: sum(z^2) = wGw + 2*sum_blk cv*(w.S3) + 1024*sum cv^2
// grid = 128 (o), block 128 (t = c)
__global__ __launch_bounds__(128) void k_stats(const float* __restrict__ final_w,
                                               const float* __restrict__ final_g,
                                               const float* __restrict__ final_b,
                                               float* __restrict__ ws) {
    int o = blockIdx.x, t = threadIdx.x;
    __shared__ __align__(16) float wlds[128];
    __shared__ __align__(16) float cvl[64];
    __shared__ float rbuf[4];
    wlds[t] = final_w[(size_t)o * 640 + t];
    __syncthreads();
    float SSQ = 0.f, SUM = 0.f;
    for (int b = 0; b < 4; ++b) {
        if (t < 64) cvl[t] = ws[CONTRIB_OFF + (size_t)(b * 128 + o) * 64 + t];
        __syncthreads();
        const float* Gb = ws + G_OFF + (size_t)b * 16384 + (size_t)t * 128;
        float a1 = 0.f;
#pragma unroll 8
        for (int k = 0; k < 128; k += 4) {
            float4 g = *(const float4*)(Gb + k);
            float4 w = *(const float4*)(&wlds[k]);
            a1 = fmaf(g.x, w.x, fmaf(g.y, w.y, fmaf(g.z, w.z, fmaf(g.w, w.w, a1))));
        }
        const float* S3p = ws + S3_OFF + (size_t)(b * 128 + t) * 64;
        float a2 = 0.f;
#pragma unroll 8
        for (int k = 0; k < 64; k += 4) {
            float4 sv = *(const float4*)(S3p + k);
            float4 cv = *(const float4*)(&cvl[k]);
            a2 = fmaf(sv.x, cv.x, fmaf(sv.y, cv.y, fmaf(sv.z, cv.z, fmaf(sv.w, cv.w, a2))));
        }
        float r1 = (a1 + 2.f * a2) * wlds[t];
        float r2 = wlds[t] * ws[SX_OFF + b * 128 + t];
        if (t < 64) {
            r1 += 1024.f * cvl[t] * cvl[t];
            r2 += 1024.f * cvl[t];
        }
#pragma unroll
        for (int k = 1; k < 64; k <<= 1) {
            r1 += __shfl_xor(r1, k);
            r2 += __shfl_xor(r2, k);
        }
        if ((t & 63) == 0) {
            rbuf[(t >> 6) * 2] = r1;
            rbuf[(t >> 6) * 2 + 1] = r2;
        }
        __syncthreads();
        SSQ += rbuf[0] + rbuf[2];
        SUM += rbuf[1] + rbuf[3];
        __syncthreads();
    }
    if (t == 0) {
        float mean = SUM / 262144.f;
        float var = SSQ / 262144.f - mean * mean;
        float sc = final_g[o] * rsqrtf(var + 1e-5f);
        ws[SCALEF_OFF + o] = sc;
        ws[SHIFTF_OFF + o] = final_b[o] - mean * sc;
    }
}

// K5: out[b,o,p] = (MFMA(W0,x) + contrib) * scale[o] + shift[o].
// grid = 2048 (b*512 + ptile of 128), block 256 (4 waves; wave = 32 p)
__global__ __launch_bounds__(256) void k_out(const float* __restrict__ x,
                                             const float* __restrict__ final_w,
                                             const float* __restrict__ ws,
                                             float* __restrict__ out) {
    __shared__ uint4 wtileq[2048];  // [128 o][128 c] bf16, swizzled, 32KB
    __shared__ float scl[128], shf[128], cvs[512];
    unsigned char* wtile = (unsigned char*)wtileq;
    int wgid = blockIdx.x;
    int b = wgid >> 9, pt = wgid & 511;
    int p0 = pt * 128;
    int t = threadIdx.x, l = t & 63, wv = t >> 6;
    // stage W0 (cols 0..127 of final_w) as bf16 [o][c]
#pragma unroll
    for (int it = 0; it < 32; ++it) {
        int pid = it * 256 + t;  // 8192 pairs
        int o = pid >> 6, cp = (pid & 63) * 2;
        float2 f = *(const float2*)(final_w + (size_t)o * 640 + cp);
        unsigned int u = bfpair(f.x, f.y);
        int wa = (o * 256 + cp * 2) ^ ((o & 7) << 4);
        *(unsigned int*)(wtile + wa) = u;
    }
    if (t < 128) {
        scl[t] = ws[SCALEF_OFF + t];
        shf[t] = ws[SHIFTF_OFF + t];
    }
    int i3 = pt >> 6, jb = (pt & 1) * 4;
    for (int q = t; q < 512; q += 256) {
        int o = q >> 2, jj = q & 3;
        cvs[q] = ws[CONTRIB_OFF + (size_t)(b * 128 + o) * 64 + i3 * 8 + jb + jj];
    }
    __syncthreads();

    const float* xb = x + (size_t)b * C_ * P_;
    int pw = p0 + wv * 32;
    f32x4 acc[8][2];
#pragma unroll
    for (int i = 0; i < 8; ++i) {
        acc[i][0] = (f32x4){0.f, 0.f, 0.f, 0.f};
        acc[i][1] = (f32x4){0.f, 0.f, 0.f, 0.f};
    }
#pragma unroll
    for (int ks = 0; ks < 4; ++ks) {
        short8 bf[2];
#pragma unroll
        for (int nt = 0; nt < 2; ++nt) {
            const float* xp = xb + (size_t)(ks * 32 + (l >> 4) * 8) * P_ + (pw + nt * 16 + (l & 15));
            float f0 = xp[0 * P_], f1 = xp[1 * P_], f2 = xp[2 * P_], f3 = xp[3 * P_];
            float f4 = xp[4 * P_], f5 = xp[5 * P_], f6 = xp[6 * P_], f7 = xp[7 * P_];
            union { uint4 u; short8 s; } cvtu;
            cvtu.u = make_uint4(bfpair(f0, f1), bfpair(f2, f3), bfpair(f4, f5), bfpair(f6, f7));
            bf[nt] = cvtu.s;
        }
#pragma unroll
        for (int mt = 0; mt < 8; ++mt) {
            int ra = ((mt * 16 + (l & 15)) * 256 + ks * 64 + (l >> 4) * 16) ^ ((l & 7) << 4);
            short8 af = *(const short8*)(wtile + ra);
            acc[mt][0] = __builtin_amdgcn_mfma_f32_16x16x32_bf16(af, bf[0], acc[mt][0], 0, 0, 0);
            acc[mt][1] = __builtin_amdgcn_mfma_f32_16x16x32_bf16(af, bf[1], acc[mt][1], 0, 0, 0);
        }
    }
    // epilogue: +contrib, *scale+shift, store
#pragma unroll
    for (int mt = 0; mt < 8; ++mt)
#pragma unroll
        for (int nt = 0; nt < 2; ++nt) {
            int p = pw + nt * 16 + (l & 15);
            int jj = ((p & 255) >> 5) & 3;
#pragma unroll
            for (int r = 0; r < 4; ++r) {
                int o = mt * 16 + (l >> 4) * 4 + r;
                float z = acc[mt][nt][r] + cvs[o * 4 + jj];
                out[(size_t)(b * 128 + o) * P_ + p] = fmaf(z, scl[o], shf[o]);
            }
        }
}

extern "C" void kernel_launch(void* const* d_in, const int* in_sizes, int n_in,
                              void* d_out, int out_size, void* d_ws, size_t ws_size,
                              hipStream_t stream) {
    const float* x = (const float*)d_in[0];
    const float* conv_w = (const float*)d_in[1];
    const float* conv_g = (const float*)d_in[2];
    const float* conv_b = (const float*)d_in[3];
    const float* final_w = (const float*)d_in[4];
    const float* final_g = (const float*)d_in[5];
    const float* final_b = (const float*)d_in[6];
    float* out = (float*)d_out;
    float* ws = (float*)d_ws;

    // single fused pass over x: fp32-exact block max/sum partials + bf16 Gram
    // (Gram partials live in d_out scratch until k_reduceG; k_out overwrites d_out)
    k_gram_pool<<<512, 256, 0, stream>>>(x, ws, out);
    k_reduceG<<<256, 256, 0, stream>>>(out, ws);
    k_reduceMS<<<512, 256, 0, stream>>>(ws);
    k_conv_pool<<<64, 256, 0, stream>>>(conv_w, ws);
    k_bnstats_d<<<2, 256, 0, stream>>>(conv_g, conv_b, ws);
    k_contrib<<<B_ * 64, 128, 0, stream>>>(final_w, ws);
    k_stats<<<128, 128, 0, stream>>>(final_w, final_g, final_b, ws);
    k_out<<<2048, 256, 0, stream>>>(x, final_w, ws, out);
}